// Round 6
// baseline (181.392 us; speedup 1.0000x reference)
//
#include <hip/hip_runtime.h>
#include <hip/hip_fp16.h>
#include <math.h>

#define C_CLS   64
#define K_SHOTS 512
#define D_DIM   2048
#define BPC     16                        // blocks per class
#define ROWS_PER_BLOCK (K_SHOTS / BPC)    // 32
#define NWAVES  4
#define ROWS_PER_WAVE (ROWS_PER_BLOCK / NWAVES)  // 8
#define NBLK    (C_CLS * BPC)             // 1024
#define NF4     8                         // pass0: float4 chunks/lane/row (fp32)
#define NH4     4                         // pass1/2: float4(=8 half) chunks/lane/row

typedef float v4f __attribute__((ext_vector_type(4)));

// nontemporal fp32 load: keep pass-0's one-shot 256 MiB stream from evicting
// the fp16 z_sq copy we want resident in Infinity Cache for passes 1-2.
__device__ __forceinline__ float4 ntload4(const float* p) {
    v4f v = __builtin_nontemporal_load((const v4f*)p);
    float4 r; r.x = v.x; r.y = v.y; r.z = v.z; r.w = v.w; return r;
}

__device__ __forceinline__ uint2 pack4(float4 v) {
    union { uint2 u; __half2 h[2]; } pk;
    pk.h[0] = __floats2half2_rn(v.x, v.y);
    pk.h[1] = __floats2half2_rn(v.z, v.w);
    return pk.u;
}

__device__ __forceinline__ float wave_reduce_sum(float v) {
#pragma unroll
    for (int off = 32; off > 0; off >>= 1)
        v += __shfl_xor(v, off, 64);
    return v;
}

// Pass 0 (iter 1): read fp32 z (nontemporal), per-row squash scale, write
// z_sq = sc*z as fp16, accumulate uniform-weight partials. Weight sum is the
// constant 512/class, so no part_e here.
__global__ __launch_bounds__(256)
void route_pass0(const float* __restrict__ z,
                 __half* __restrict__ z16,
                 float* __restrict__ part_s)
{
    __shared__ float4 s_comb[NWAVES][D_DIM / 4];  // 32 KB

    const int blk  = blockIdx.x;
    const int cls  = blk >> 4;
    const int bic  = blk & (BPC - 1);
    const int lane = threadIdx.x & 63;
    const int wid  = threadIdx.x >> 6;
    const int t    = threadIdx.x;

    float4 acc[NF4];
#pragma unroll
    for (int i = 0; i < NF4; ++i) acc[i] = make_float4(0.f, 0.f, 0.f, 0.f);

    const int k0 = bic * ROWS_PER_BLOCK + wid * ROWS_PER_WAVE;
    const float* __restrict__ zb = z + ((size_t)cls * K_SHOTS + k0) * D_DIM;

    float4 zcur[NF4];
#pragma unroll
    for (int i = 0; i < NF4; ++i) zcur[i] = ntload4(zb + 4 * (lane + i * 64));

#pragma unroll
    for (int r = 0; r < ROWS_PER_WAVE; ++r) {
        float4 znext[NF4];
        if (r + 1 < ROWS_PER_WAVE) {
            const float* zn = zb + (size_t)(r + 1) * D_DIM;
#pragma unroll
            for (int i = 0; i < NF4; ++i) znext[i] = ntload4(zn + 4 * (lane + i * 64));
        }
        float n2 = 0.f;
#pragma unroll
        for (int i = 0; i < NF4; ++i)
            n2 += zcur[i].x * zcur[i].x + zcur[i].y * zcur[i].y
                + zcur[i].z * zcur[i].z + zcur[i].w * zcur[i].w;
        n2 = wave_reduce_sum(n2);
        const float sc = sqrtf(n2) / (1.f + n2);

        uint2* p16 = (uint2*)(z16 + ((size_t)cls * K_SHOTS + k0 + r) * D_DIM);
#pragma unroll
        for (int i = 0; i < NF4; ++i) {
            float4 s;
            s.x = sc * zcur[i].x; s.y = sc * zcur[i].y;
            s.z = sc * zcur[i].z; s.w = sc * zcur[i].w;
            p16[lane + i * 64] = pack4(s);
            acc[i].x += s.x; acc[i].y += s.y; acc[i].z += s.z; acc[i].w += s.w;
        }
        if (r + 1 < ROWS_PER_WAVE) {
#pragma unroll
            for (int i = 0; i < NF4; ++i) zcur[i] = znext[i];
        }
    }

#pragma unroll
    for (int i = 0; i < NF4; ++i) s_comb[wid][lane + i * 64] = acc[i];
    __syncthreads();

    float4* ps = (float4*)(part_s + (size_t)blk * D_DIM);
#pragma unroll
    for (int j = 0; j < 2; ++j) {
        const int f = t + j * 256;
        const float4 a  = s_comb[0][f];
        const float4 b4 = s_comb[1][f];
        const float4 c4 = s_comb[2][f];
        const float4 d4 = s_comb[3][f];
        float4 s;
        s.x = (a.x + b4.x) + (c4.x + d4.x);
        s.y = (a.y + b4.y) + (c4.y + d4.y);
        s.z = (a.z + b4.z) + (c4.z + d4.z);
        s.w = (a.w + b4.w) + (c4.w + d4.w);
        ps[f] = s;
    }
}

// Passes 1/2 (iters 2/3): INLINE per-class reduce of the previous pass's 16
// partials (redundant per block, fixed order -> deterministic; kernel
// boundary supplies coherence, no atomics), then stream fp16 z_sq.
// First-row z16 loads are issued before the reduce so its latency hides.
// PASS 1: esum_prev = 512 exactly (uniform weights); stores b1; reverse walk.
// PASS 2: esum_prev from pe_in; adds b1; forward walk.
template <int PASS>
__global__ __launch_bounds__(256)
void route_pass_h(const __half* __restrict__ z16,
                  float* __restrict__ bvec,
                  const float* __restrict__ ps_in,
                  const float* __restrict__ pe_in,
                  float* __restrict__ ps_out,
                  float* __restrict__ pe_out)
{
    __shared__ float4 s_comb[NWAVES][D_DIM / 4];  // 32 KB; s_comb[0] doubles as c-stage
    __shared__ float  e_comb[NWAVES];

    const int rawblk = blockIdx.x;
    const int blk  = (PASS == 1) ? (NBLK - 1 - rawblk) : rawblk;
    const int cls  = blk >> 4;
    const int bic  = blk & (BPC - 1);
    const int lane = threadIdx.x & 63;
    const int wid  = threadIdx.x >> 6;
    const int t    = threadIdx.x;

    const int k0 = bic * ROWS_PER_BLOCK + wid * ROWS_PER_WAVE;
    const float4* __restrict__ zb =
        (const float4*)(z16 + ((size_t)cls * K_SHOTS + k0) * D_DIM);  // row = D/8 float4s

    const int r0    = (PASS == 1) ? (ROWS_PER_WAVE - 1) : 0;
    const int rstep = (PASS == 1) ? -1 : 1;

    // (1) issue first-row loads early — independent of the reduce below
    float4 zcur[NH4];
#pragma unroll
    for (int j = 0; j < NH4; ++j)
        zcur[j] = zb[(size_t)r0 * (D_DIM / 8) + lane + j * 64];

    // (2) inline class reduce: c_prev = squash(sum(ps_in)/esum_prev)
    float esum_prev;
    if (PASS == 1) {
        esum_prev = (float)K_SHOTS;
    } else {
        esum_prev = 0.f;
#pragma unroll
        for (int p = 0; p < BPC; ++p) esum_prev += pe_in[cls * BPC + p];
    }
    const float inv = 1.f / esum_prev;

    float4 m[2];
    float n2p = 0.f;
#pragma unroll
    for (int j = 0; j < 2; ++j) {
        const int f = t + j * 256;
        float4 s = make_float4(0.f, 0.f, 0.f, 0.f);
#pragma unroll
        for (int p = 0; p < BPC; ++p) {
            const float4 v =
                ((const float4*)(ps_in + (size_t)(cls * BPC + p) * D_DIM))[f];
            s.x += v.x; s.y += v.y; s.z += v.z; s.w += v.w;
        }
        m[j].x = s.x * inv; m[j].y = s.y * inv;
        m[j].z = s.z * inv; m[j].w = s.w * inv;
        n2p += m[j].x * m[j].x + m[j].y * m[j].y
             + m[j].z * m[j].z + m[j].w * m[j].w;
    }
    float n2 = wave_reduce_sum(n2p);
    if (lane == 0) e_comb[wid] = n2;
    __syncthreads();
    n2 = (e_comb[0] + e_comb[1]) + (e_comb[2] + e_comb[3]);
    const float fac = sqrtf(n2) / (1.f + n2);
#pragma unroll
    for (int j = 0; j < 2; ++j) {
        const int f = t + j * 256;
        float4 cv;
        cv.x = m[j].x * fac; cv.y = m[j].y * fac;
        cv.z = m[j].z * fac; cv.w = m[j].w * fac;
        s_comb[0][f] = cv;
    }
    __syncthreads();

    // lane fragments of c: halfs 8*(lane+j*64)..+7 -> two float4s each
    float4 cpA[NH4], cpB[NH4];
#pragma unroll
    for (int j = 0; j < NH4; ++j) {
        const int c2i = 2 * (lane + j * 64);
        cpA[j] = s_comb[0][c2i];
        cpB[j] = s_comb[0][c2i + 1];
    }
    __syncthreads();   // protect the s_comb[0] overlay before combine reuses it

    float4 acc[2 * NH4];
#pragma unroll
    for (int i = 0; i < 2 * NH4; ++i) acc[i] = make_float4(0.f, 0.f, 0.f, 0.f);
    float esum = 0.f;

#pragma unroll
    for (int rr = 0; rr < ROWS_PER_WAVE; ++rr) {
        const int r = r0 + rr * rstep;
        float4 znext[NH4];
        if (rr + 1 < ROWS_PER_WAVE) {
            const float4* zn = zb + (size_t)(r + rstep) * (D_DIM / 8);
#pragma unroll
            for (int j = 0; j < NH4; ++j) znext[j] = zn[lane + j * 64];
        }

        float dot = 0.f;
#pragma unroll
        for (int j = 0; j < NH4; ++j) {
            const __half2* hp = (const __half2*)&zcur[j];
            const float2 a0 = __half22float2(hp[0]);
            const float2 a1 = __half22float2(hp[1]);
            const float2 a2 = __half22float2(hp[2]);
            const float2 a3 = __half22float2(hp[3]);
            dot += a0.x * cpA[j].x + a0.y * cpA[j].y
                 + a1.x * cpA[j].z + a1.y * cpA[j].w
                 + a2.x * cpB[j].x + a2.y * cpB[j].y
                 + a3.x * cpB[j].z + a3.y * cpB[j].w;
        }
        dot = wave_reduce_sum(dot);

        const int k = k0 + r;
        float bnew = dot;
        if (PASS == 2) bnew += bvec[cls * K_SHOTS + k];
        if (PASS == 1 && lane == 0) bvec[cls * K_SHOTS + k] = bnew;
        const float w = expf(bnew);          // unnormalized softmax weight
        esum += w;

#pragma unroll
        for (int j = 0; j < NH4; ++j) {
            const __half2* hp = (const __half2*)&zcur[j];
            const float2 a0 = __half22float2(hp[0]);
            const float2 a1 = __half22float2(hp[1]);
            const float2 a2 = __half22float2(hp[2]);
            const float2 a3 = __half22float2(hp[3]);
            acc[2 * j].x     += w * a0.x;  acc[2 * j].y     += w * a0.y;
            acc[2 * j].z     += w * a1.x;  acc[2 * j].w     += w * a1.y;
            acc[2 * j + 1].x += w * a2.x;  acc[2 * j + 1].y += w * a2.y;
            acc[2 * j + 1].z += w * a3.x;  acc[2 * j + 1].w += w * a3.y;
        }

        if (rr + 1 < ROWS_PER_WAVE) {
#pragma unroll
            for (int j = 0; j < NH4; ++j) zcur[j] = znext[j];
        }
    }

    // deterministic 4-wave combine via LDS, publish block partial
#pragma unroll
    for (int j = 0; j < NH4; ++j) {
        const int c2i = 2 * (lane + j * 64);
        s_comb[wid][c2i]     = acc[2 * j];
        s_comb[wid][c2i + 1] = acc[2 * j + 1];
    }
    if (lane == 0) e_comb[wid] = esum;
    __syncthreads();

    float4* ps = (float4*)(ps_out + (size_t)blk * D_DIM);
#pragma unroll
    for (int j = 0; j < 2; ++j) {
        const int f = t + j * 256;
        const float4 a  = s_comb[0][f];
        const float4 b4 = s_comb[1][f];
        const float4 c4 = s_comb[2][f];
        const float4 d4 = s_comb[3][f];
        float4 s;
        s.x = (a.x + b4.x) + (c4.x + d4.x);
        s.y = (a.y + b4.y) + (c4.y + d4.y);
        s.z = (a.z + b4.z) + (c4.z + d4.z);
        s.w = (a.w + b4.w) + (c4.w + d4.w);
        ps[f] = s;
    }
    if (t == 0) pe_out[blk] = (e_comb[0] + e_comb[1]) + (e_comb[2] + e_comb[3]);
}

// Final: sum the BPC partials per class (fixed order), normalize by sum(exp),
// squash, write output c.
__global__ __launch_bounds__(256)
void reduce_squash(const float* __restrict__ part_s,
                   const float* __restrict__ part_e,
                   float* __restrict__ c_out)
{
    __shared__ float wred[NWAVES];
    const int cls  = blockIdx.x;
    const int t    = threadIdx.x;
    const int lane = t & 63;
    const int wid  = t >> 6;

    float esum = 0.f;
#pragma unroll
    for (int p = 0; p < BPC; ++p) esum += part_e[cls * BPC + p];
    const float inv = 1.f / esum;

    float4 m[2];
    float n2p = 0.f;
#pragma unroll
    for (int j = 0; j < 2; ++j) {
        const int f = t + j * 256;
        float4 s = make_float4(0.f, 0.f, 0.f, 0.f);
        for (int p = 0; p < BPC; ++p) {
            const float4 v =
                ((const float4*)(part_s + (size_t)(cls * BPC + p) * D_DIM))[f];
            s.x += v.x; s.y += v.y; s.z += v.z; s.w += v.w;
        }
        m[j].x = s.x * inv; m[j].y = s.y * inv;
        m[j].z = s.z * inv; m[j].w = s.w * inv;
        n2p += m[j].x * m[j].x + m[j].y * m[j].y
             + m[j].z * m[j].z + m[j].w * m[j].w;
    }
    float n2 = wave_reduce_sum(n2p);
    if (lane == 0) wred[wid] = n2;
    __syncthreads();
    n2 = (wred[0] + wred[1]) + (wred[2] + wred[3]);
    const float fac = sqrtf(n2) / (1.f + n2);

    float4* co = (float4*)(c_out + (size_t)cls * D_DIM);
#pragma unroll
    for (int j = 0; j < 2; ++j) {
        const int f = t + j * 256;
        float4 o;
        o.x = m[j].x * fac; o.y = m[j].y * fac;
        o.z = m[j].z * fac; o.w = m[j].w * fac;
        co[f] = o;
    }
}

extern "C" void kernel_launch(void* const* d_in, const int* in_sizes, int n_in,
                              void* d_out, int out_size, void* d_ws, size_t ws_size,
                              hipStream_t stream)
{
    const float* z = (const float*)d_in[0];
    float* out = (float*)d_out;
    float* ws  = (float*)d_ws;

    float* bvec    = ws;                                  // C*K
    float* part_s0 = bvec + C_CLS * K_SHOTS;              // NBLK*D (8 MiB)
    float* part_s1 = part_s0 + (size_t)NBLK * D_DIM;      // NBLK*D (8 MiB)
    float* part_e1 = part_s1 + (size_t)NBLK * D_DIM;      // NBLK
    float* part_e2 = part_e1 + NBLK;                      // NBLK
    __half* z16    = (__half*)(part_e2 + NBLK);           // C*K*D halfs (128 MiB)
    // total ws: ~145 MB (< 1 GB)

    // iter 1: fp32 z -> scale + z16 + uniform partials
    route_pass0<<<NBLK, 256, 0, stream>>>(z, z16, part_s0);
    // iter 2: inline reduce(part_s0, esum=512) -> c1; stream z16; b1 stored
    route_pass_h<1><<<NBLK, 256, 0, stream>>>(z16, bvec, part_s0, nullptr,
                                              part_s1, part_e1);
    // iter 3: inline reduce(part_s1, part_e1) -> c2; stream z16; b2 = b1 + dot
    route_pass_h<2><<<NBLK, 256, 0, stream>>>(z16, bvec, part_s1, part_e1,
                                              part_s0, part_e2);
    // final: reduce(part_s0, part_e2) -> squash -> out
    reduce_squash<<<C_CLS, 256, 0, stream>>>(part_s0, part_e2, out);
}

// Round 7
// 155.799 us; speedup vs baseline: 1.1643x; 1.1643x over previous
//
#include <hip/hip_runtime.h>
#include <hip/hip_fp16.h>
#include <math.h>

#define C_CLS   64
#define K_SHOTS 512
#define D_DIM   2048
#define BPC     16                        // blocks per class
#define ROWS_PER_BLOCK (K_SHOTS / BPC)    // 32
#define NWAVES  4
#define ROWS_PER_WAVE (ROWS_PER_BLOCK / NWAVES)  // 8
#define NBLK    (C_CLS * BPC)             // 1024
#define NF4     8                         // pass0: float4 chunks/lane/row (fp32)
#define NH4     4                         // pass1/2: float4(=8 half) chunks/lane/row

__device__ __forceinline__ uint2 pack4(float4 v) {
    union { uint2 u; __half2 h[2]; } pk;
    pk.h[0] = __floats2half2_rn(v.x, v.y);
    pk.h[1] = __floats2half2_rn(v.z, v.w);
    return pk.u;
}

__device__ __forceinline__ float wave_reduce_sum(float v) {
#pragma unroll
    for (int off = 32; off > 0; off >>= 1)
        v += __shfl_xor(v, off, 64);
    return v;
}

// Pass 0 (iter 1): read fp32 z (plain cached loads — nt hint dropped, it
// bought nothing and may stream below the plain-load ceiling), per-row squash
// scale, write z_sq = sc*z as fp16, accumulate uniform-weight partials
// (written as fp16 — halves boundary traffic; error ~1e-8 on c).
__global__ __launch_bounds__(256)
void route_pass0(const float* __restrict__ z,
                 __half* __restrict__ z16,
                 __half* __restrict__ part_s,
                 float* __restrict__ part_e)
{
    __shared__ float4 s_comb[NWAVES][D_DIM / 4];  // 32 KB
    __shared__ float  e_comb[NWAVES];

    const int blk  = blockIdx.x;
    const int cls  = blk >> 4;
    const int bic  = blk & (BPC - 1);
    const int lane = threadIdx.x & 63;
    const int wid  = threadIdx.x >> 6;
    const int t    = threadIdx.x;

    float4 acc[NF4];
#pragma unroll
    for (int i = 0; i < NF4; ++i) acc[i] = make_float4(0.f, 0.f, 0.f, 0.f);
    float esum = 0.f;

    const int k0 = bic * ROWS_PER_BLOCK + wid * ROWS_PER_WAVE;
    const float4* __restrict__ zb =
        (const float4*)(z + ((size_t)cls * K_SHOTS + k0) * D_DIM);

    float4 zcur[NF4];
#pragma unroll
    for (int i = 0; i < NF4; ++i) zcur[i] = zb[lane + i * 64];

#pragma unroll
    for (int r = 0; r < ROWS_PER_WAVE; ++r) {
        float4 znext[NF4];
        if (r + 1 < ROWS_PER_WAVE) {
            const float4* zn = zb + (size_t)(r + 1) * (D_DIM / 4);
#pragma unroll
            for (int i = 0; i < NF4; ++i) znext[i] = zn[lane + i * 64];
        }
        float n2 = 0.f;
#pragma unroll
        for (int i = 0; i < NF4; ++i)
            n2 += zcur[i].x * zcur[i].x + zcur[i].y * zcur[i].y
                + zcur[i].z * zcur[i].z + zcur[i].w * zcur[i].w;
        n2 = wave_reduce_sum(n2);
        const float sc = sqrtf(n2) / (1.f + n2);

        uint2* p16 = (uint2*)(z16 + ((size_t)cls * K_SHOTS + k0 + r) * D_DIM);
#pragma unroll
        for (int i = 0; i < NF4; ++i) {
            float4 s;
            s.x = sc * zcur[i].x; s.y = sc * zcur[i].y;
            s.z = sc * zcur[i].z; s.w = sc * zcur[i].w;
            p16[lane + i * 64] = pack4(s);
            acc[i].x += s.x; acc[i].y += s.y; acc[i].z += s.z; acc[i].w += s.w;
        }
        esum += 1.f;   // w = 1 (softmax(0) uniform; normalized later)

        if (r + 1 < ROWS_PER_WAVE) {
#pragma unroll
            for (int i = 0; i < NF4; ++i) zcur[i] = znext[i];
        }
    }

    // deterministic 4-wave combine via LDS, publish block partial (fp16)
#pragma unroll
    for (int i = 0; i < NF4; ++i) s_comb[wid][lane + i * 64] = acc[i];
    if (lane == 0) e_comb[wid] = esum;
    __syncthreads();

    uint2* ps = (uint2*)(part_s + (size_t)blk * D_DIM);
#pragma unroll
    for (int j = 0; j < 2; ++j) {
        const int f = t + j * 256;
        const float4 a  = s_comb[0][f];
        const float4 b4 = s_comb[1][f];
        const float4 c4 = s_comb[2][f];
        const float4 d4 = s_comb[3][f];
        float4 s;
        s.x = (a.x + b4.x) + (c4.x + d4.x);
        s.y = (a.y + b4.y) + (c4.y + d4.y);
        s.z = (a.z + b4.z) + (c4.z + d4.z);
        s.w = (a.w + b4.w) + (c4.w + d4.w);
        ps[f] = pack4(s);
    }
    if (t == 0) part_e[blk] = (e_comb[0] + e_comb[1]) + (e_comb[2] + e_comb[3]);
}

// Passes 1/2 (iters 2/3): read fp16 z_sq; b = dot(z16, c_prev) directly
// (sc baked in). PASS 1 stores b1 and walks in reverse (MRU-first re-scan);
// PASS 2 adds b1 and walks forward.
template <int PASS>
__global__ __launch_bounds__(256)
void route_pass_h(const __half* __restrict__ z16,
                  float* __restrict__ bvec,
                  const float* __restrict__ c_prev,
                  __half* __restrict__ part_s,
                  float* __restrict__ part_e)
{
    __shared__ float4 s_comb[NWAVES][D_DIM / 4];  // 32 KB
    __shared__ float  e_comb[NWAVES];

    const int rawblk = blockIdx.x;
    const int blk  = (PASS == 1) ? (NBLK - 1 - rawblk) : rawblk;
    const int cls  = blk >> 4;
    const int bic  = blk & (BPC - 1);
    const int lane = threadIdx.x & 63;
    const int wid  = threadIdx.x >> 6;
    const int t    = threadIdx.x;

    // c_prev fragment: lane covers halfs 8*(lane+j*64)..+7 -> two float4s each
    const float4* cp4 = (const float4*)(c_prev + (size_t)cls * D_DIM);
    float4 cpA[NH4], cpB[NH4];
#pragma unroll
    for (int j = 0; j < NH4; ++j) {
        const int c2i = 2 * (lane + j * 64);
        cpA[j] = cp4[c2i];
        cpB[j] = cp4[c2i + 1];
    }

    float4 acc[2 * NH4];
#pragma unroll
    for (int i = 0; i < 2 * NH4; ++i) acc[i] = make_float4(0.f, 0.f, 0.f, 0.f);
    float esum = 0.f;

    const int k0 = bic * ROWS_PER_BLOCK + wid * ROWS_PER_WAVE;
    const float4* __restrict__ zb =
        (const float4*)(z16 + ((size_t)cls * K_SHOTS + k0) * D_DIM);  // row = D/8 float4s

    const int r0    = (PASS == 1) ? (ROWS_PER_WAVE - 1) : 0;
    const int rstep = (PASS == 1) ? -1 : 1;

    float4 zcur[NH4];
#pragma unroll
    for (int j = 0; j < NH4; ++j)
        zcur[j] = zb[(size_t)r0 * (D_DIM / 8) + lane + j * 64];

#pragma unroll
    for (int rr = 0; rr < ROWS_PER_WAVE; ++rr) {
        const int r = r0 + rr * rstep;
        float4 znext[NH4];
        if (rr + 1 < ROWS_PER_WAVE) {
            const float4* zn = zb + (size_t)(r + rstep) * (D_DIM / 8);
#pragma unroll
            for (int j = 0; j < NH4; ++j) znext[j] = zn[lane + j * 64];
        }

        float dot = 0.f;
#pragma unroll
        for (int j = 0; j < NH4; ++j) {
            const __half2* hp = (const __half2*)&zcur[j];
            const float2 a0 = __half22float2(hp[0]);
            const float2 a1 = __half22float2(hp[1]);
            const float2 a2 = __half22float2(hp[2]);
            const float2 a3 = __half22float2(hp[3]);
            dot += a0.x * cpA[j].x + a0.y * cpA[j].y
                 + a1.x * cpA[j].z + a1.y * cpA[j].w
                 + a2.x * cpB[j].x + a2.y * cpB[j].y
                 + a3.x * cpB[j].z + a3.y * cpB[j].w;
        }
        dot = wave_reduce_sum(dot);

        const int k = k0 + r;
        float bnew = dot;
        if (PASS == 2) bnew += bvec[cls * K_SHOTS + k];
        if (PASS == 1 && lane == 0) bvec[cls * K_SHOTS + k] = bnew;
        const float w = expf(bnew);          // unnormalized softmax weight
        esum += w;

#pragma unroll
        for (int j = 0; j < NH4; ++j) {
            const __half2* hp = (const __half2*)&zcur[j];
            const float2 a0 = __half22float2(hp[0]);
            const float2 a1 = __half22float2(hp[1]);
            const float2 a2 = __half22float2(hp[2]);
            const float2 a3 = __half22float2(hp[3]);
            acc[2 * j].x     += w * a0.x;  acc[2 * j].y     += w * a0.y;
            acc[2 * j].z     += w * a1.x;  acc[2 * j].w     += w * a1.y;
            acc[2 * j + 1].x += w * a2.x;  acc[2 * j + 1].y += w * a2.y;
            acc[2 * j + 1].z += w * a3.x;  acc[2 * j + 1].w += w * a3.y;
        }

        if (rr + 1 < ROWS_PER_WAVE) {
#pragma unroll
            for (int j = 0; j < NH4; ++j) zcur[j] = znext[j];
        }
    }

    // deterministic 4-wave combine via LDS, publish block partial (fp16)
#pragma unroll
    for (int j = 0; j < NH4; ++j) {
        const int c2i = 2 * (lane + j * 64);
        s_comb[wid][c2i]     = acc[2 * j];
        s_comb[wid][c2i + 1] = acc[2 * j + 1];
    }
    if (lane == 0) e_comb[wid] = esum;
    __syncthreads();

    uint2* ps = (uint2*)(part_s + (size_t)blk * D_DIM);
#pragma unroll
    for (int j = 0; j < 2; ++j) {
        const int f = t + j * 256;
        const float4 a  = s_comb[0][f];
        const float4 b4 = s_comb[1][f];
        const float4 c4 = s_comb[2][f];
        const float4 d4 = s_comb[3][f];
        float4 s;
        s.x = (a.x + b4.x) + (c4.x + d4.x);
        s.y = (a.y + b4.y) + (c4.y + d4.y);
        s.z = (a.z + b4.z) + (c4.z + d4.z);
        s.w = (a.w + b4.w) + (c4.w + d4.w);
        ps[f] = pack4(s);
    }
    if (t == 0) part_e[blk] = (e_comb[0] + e_comb[1]) + (e_comb[2] + e_comb[3]);
}

// Sum the BPC fp16 partials per class (fixed order -> deterministic, fp32
// accumulation), normalize by sum(weights), squash, write c (or output).
__global__ __launch_bounds__(256)
void reduce_squash(const __half* __restrict__ part_s,
                   const float* __restrict__ part_e,
                   float* __restrict__ c_out)
{
    __shared__ float wred[NWAVES];
    const int cls  = blockIdx.x;
    const int t    = threadIdx.x;
    const int lane = t & 63;
    const int wid  = t >> 6;

    float esum = 0.f;
#pragma unroll
    for (int p = 0; p < BPC; ++p) esum += part_e[cls * BPC + p];
    const float inv = 1.f / esum;

    float4 m[2];
    float n2p = 0.f;
#pragma unroll
    for (int j = 0; j < 2; ++j) {
        const int f = t + j * 256;
        float4 s = make_float4(0.f, 0.f, 0.f, 0.f);
#pragma unroll
        for (int p = 0; p < BPC; ++p) {
            const uint2 v =
                ((const uint2*)(part_s + (size_t)(cls * BPC + p) * D_DIM))[f];
            const __half2* hv = (const __half2*)&v;
            const float2 lo = __half22float2(hv[0]);
            const float2 hi = __half22float2(hv[1]);
            s.x += lo.x; s.y += lo.y; s.z += hi.x; s.w += hi.y;
        }
        m[j].x = s.x * inv; m[j].y = s.y * inv;
        m[j].z = s.z * inv; m[j].w = s.w * inv;
        n2p += m[j].x * m[j].x + m[j].y * m[j].y
             + m[j].z * m[j].z + m[j].w * m[j].w;
    }
    float n2 = wave_reduce_sum(n2p);
    if (lane == 0) wred[wid] = n2;
    __syncthreads();
    n2 = (wred[0] + wred[1]) + (wred[2] + wred[3]);
    const float fac = sqrtf(n2) / (1.f + n2);

    float4* co = (float4*)(c_out + (size_t)cls * D_DIM);
#pragma unroll
    for (int j = 0; j < 2; ++j) {
        const int f = t + j * 256;
        float4 o;
        o.x = m[j].x * fac; o.y = m[j].y * fac;
        o.z = m[j].z * fac; o.w = m[j].w * fac;
        co[f] = o;
    }
}

extern "C" void kernel_launch(void* const* d_in, const int* in_sizes, int n_in,
                              void* d_out, int out_size, void* d_ws, size_t ws_size,
                              hipStream_t stream)
{
    const float* z = (const float*)d_in[0];
    float* out = (float*)d_out;
    float* ws  = (float*)d_ws;

    float*  bvec   = ws;                                  // C*K f32
    float*  part_e = bvec + C_CLS * K_SHOTS;              // NBLK f32
    float*  c_buf  = part_e + NBLK;                       // C*D f32
    __half* part_s = (__half*)(c_buf + (size_t)C_CLS * D_DIM);   // NBLK*D half (4 MiB)
    __half* z16    = part_s + (size_t)NBLK * D_DIM;       // C*K*D half (128 MiB)
    // total ws: ~133 MB (< 1 GB)

    route_pass0<<<NBLK, 256, 0, stream>>>(z, z16, part_s, part_e);
    reduce_squash<<<C_CLS, 256, 0, stream>>>(part_s, part_e, c_buf);

    route_pass_h<1><<<NBLK, 256, 0, stream>>>(z16, bvec, c_buf, part_s, part_e);
    reduce_squash<<<C_CLS, 256, 0, stream>>>(part_s, part_e, c_buf);

    route_pass_h<2><<<NBLK, 256, 0, stream>>>(z16, bvec, c_buf, part_s, part_e);
    reduce_squash<<<C_CLS, 256, 0, stream>>>(part_s, part_e, out);
}

// Round 9
// 155.132 us; speedup vs baseline: 1.1693x; 1.0043x over previous
//
#include <hip/hip_runtime.h>
#include <hip/hip_cooperative_groups.h>
#include <hip/hip_fp16.h>
#include <math.h>

#define C_CLS   64
#define K_SHOTS 512
#define D_DIM   2048
#define NWAVES  4
#define NF4     8    // fp32 float4 chunks/lane/row
#define NH4     4    // fp16 float4(=8 half) chunks/lane/row

// ---- cooperative (fused) decomposition: 512 blocks = 2/CU guaranteed ----
#define BPC_C   8
#define RPB_C   (K_SHOTS / BPC_C)          // 64 rows/block
#define RPW_C   (RPB_C / NWAVES)           // 16 rows/wave
#define NBLK_C  (C_CLS * BPC_C)            // 512

// ---- fallback (6-kernel, round-7 proven) decomposition ----
#define BPC_F   16
#define RPB_F   (K_SHOTS / BPC_F)          // 32
#define RPW_F   (RPB_F / NWAVES)           // 8
#define NBLK_F  (C_CLS * BPC_F)            // 1024

namespace cg = cooperative_groups;

__device__ __forceinline__ uint2 pack4(float4 v) {
    union { uint2 u; __half2 h[2]; } pk;
    pk.h[0] = __floats2half2_rn(v.x, v.y);
    pk.h[1] = __floats2half2_rn(v.z, v.w);
    return pk.u;
}

__device__ __forceinline__ float wave_reduce_sum(float v) {
#pragma unroll
    for (int off = 32; off > 0; off >>= 1)
        v += __shfl_xor(v, off, 64);
    return v;
}

// grid-wide barrier with explicit agent-scope fences: __threadfence() emits
// the L2 writeback (release side) / L2 invalidate (acquire side) required for
// cross-XCD visibility of the non-atomic part_s/c_buf traffic.
__device__ __forceinline__ void gsync(cg::grid_group& g) {
    __threadfence();
    g.sync();
    __threadfence();
}

// =========================== cooperative fused path ========================

// per-class reduce of BPC_C fp16 partials (fixed order -> deterministic),
// normalize by inv, squash, write fp32 c row.
__device__ __forceinline__ void class_reduce_c(const __half* __restrict__ ps_cls,
                                               float inv,
                                               float* __restrict__ dst,
                                               int t, int lane, int wid,
                                               float* e_red)
{
    float4 m[2];
    float n2p = 0.f;
#pragma unroll
    for (int j = 0; j < 2; ++j) {
        const int f = t + j * 256;
        float4 s = make_float4(0.f, 0.f, 0.f, 0.f);
#pragma unroll
        for (int p = 0; p < BPC_C; ++p) {
            const uint2 v = ((const uint2*)(ps_cls + (size_t)p * D_DIM))[f];
            const __half2* hv = (const __half2*)&v;
            const float2 lo = __half22float2(hv[0]);
            const float2 hi = __half22float2(hv[1]);
            s.x += lo.x; s.y += lo.y; s.z += hi.x; s.w += hi.y;
        }
        m[j].x = s.x * inv; m[j].y = s.y * inv;
        m[j].z = s.z * inv; m[j].w = s.w * inv;
        n2p += m[j].x * m[j].x + m[j].y * m[j].y
             + m[j].z * m[j].z + m[j].w * m[j].w;
    }
    float n2 = wave_reduce_sum(n2p);
    if (lane == 0) e_red[wid] = n2;
    __syncthreads();
    n2 = (e_red[0] + e_red[1]) + (e_red[2] + e_red[3]);
    const float fac = sqrtf(n2) / (1.f + n2);
    float4* co = (float4*)dst;
#pragma unroll
    for (int j = 0; j < 2; ++j) {
        const int f = t + j * 256;
        float4 o;
        o.x = m[j].x * fac; o.y = m[j].y * fac;
        o.z = m[j].z * fac; o.w = m[j].w * fac;
        co[f] = o;
    }
    __syncthreads();   // protect e_red before later phases reuse it
}

__global__ __launch_bounds__(256, 2)   // cap VGPR<=~256 => >=2 blocks/CU => coop grid fits
void induction_fused(const float* __restrict__ z,
                     __half* __restrict__ z16,
                     __half* __restrict__ part_s,
                     float* __restrict__ part_e,
                     float* __restrict__ c_buf,
                     float* __restrict__ out)
{
    cg::grid_group grid = cg::this_grid();

    __shared__ float4 s_comb[NWAVES][D_DIM / 4];  // 32 KB
    __shared__ float  e_comb[NWAVES];

    const int blk  = blockIdx.x;
    const int cls  = blk >> 3;            // / BPC_C
    const int bic  = blk & (BPC_C - 1);
    const int lane = threadIdx.x & 63;
    const int wid  = threadIdx.x >> 6;
    const int t    = threadIdx.x;
    const int k0   = bic * RPB_C + wid * RPW_C;

    // ============ phase 0: fp32 z -> squash scale, z16, uniform partials ===
    {
        float4 acc[NF4];
#pragma unroll
        for (int i = 0; i < NF4; ++i) acc[i] = make_float4(0.f, 0.f, 0.f, 0.f);

        const float4* __restrict__ zb =
            (const float4*)(z + ((size_t)cls * K_SHOTS + k0) * D_DIM);

        float4 zcur[NF4];
#pragma unroll
        for (int i = 0; i < NF4; ++i) zcur[i] = zb[lane + i * 64];

#pragma unroll
        for (int r = 0; r < RPW_C; ++r) {
            float4 znext[NF4];
            if (r + 1 < RPW_C) {
                const float4* zn = zb + (size_t)(r + 1) * (D_DIM / 4);
#pragma unroll
                for (int i = 0; i < NF4; ++i) znext[i] = zn[lane + i * 64];
            }
            float n2 = 0.f;
#pragma unroll
            for (int i = 0; i < NF4; ++i)
                n2 += zcur[i].x * zcur[i].x + zcur[i].y * zcur[i].y
                    + zcur[i].z * zcur[i].z + zcur[i].w * zcur[i].w;
            n2 = wave_reduce_sum(n2);
            const float sc = sqrtf(n2) / (1.f + n2);

            uint2* p16 = (uint2*)(z16 + ((size_t)cls * K_SHOTS + k0 + r) * D_DIM);
#pragma unroll
            for (int i = 0; i < NF4; ++i) {
                float4 s;
                s.x = sc * zcur[i].x; s.y = sc * zcur[i].y;
                s.z = sc * zcur[i].z; s.w = sc * zcur[i].w;
                p16[lane + i * 64] = pack4(s);
                acc[i].x += s.x; acc[i].y += s.y; acc[i].z += s.z; acc[i].w += s.w;
            }
            if (r + 1 < RPW_C) {
#pragma unroll
                for (int i = 0; i < NF4; ++i) zcur[i] = znext[i];
            }
        }

#pragma unroll
        for (int i = 0; i < NF4; ++i) s_comb[wid][lane + i * 64] = acc[i];
        __syncthreads();
        uint2* ps = (uint2*)(part_s + (size_t)blk * D_DIM);
#pragma unroll
        for (int j = 0; j < 2; ++j) {
            const int f = t + j * 256;
            const float4 a  = s_comb[0][f];
            const float4 b4 = s_comb[1][f];
            const float4 c4 = s_comb[2][f];
            const float4 d4 = s_comb[3][f];
            float4 s;
            s.x = (a.x + b4.x) + (c4.x + d4.x);
            s.y = (a.y + b4.y) + (c4.y + d4.y);
            s.z = (a.z + b4.z) + (c4.z + d4.z);
            s.w = (a.w + b4.w) + (c4.w + d4.w);
            ps[f] = pack4(s);
        }
    }

    gsync(grid);   // part_s + z16 visible device-wide

    const float4* __restrict__ zh =
        (const float4*)(z16 + ((size_t)cls * K_SHOTS + k0) * D_DIM);

    // prefetch first z16 row — hides the class-reduce under the stream ramp
    float4 hcur[NH4];
#pragma unroll
    for (int j = 0; j < NH4; ++j) hcur[j] = zh[lane + j * 64];

    if (blk < C_CLS)   // softmax(0) uniform -> c1
        class_reduce_c(part_s + (size_t)blk * BPC_C * D_DIM, 1.f / (float)K_SHOTS,
                       c_buf + (size_t)blk * D_DIM, t, lane, wid, e_comb);

    gsync(grid);   // c1 ready

    float b1reg[RPW_C];
    float esum;

    // ============ phase 1: b1 = z16.c1 (kept in regs), exp weights =========
    {
        const float4* cp4 = (const float4*)(c_buf + (size_t)cls * D_DIM);
        float4 cpA[NH4], cpB[NH4];
#pragma unroll
        for (int j = 0; j < NH4; ++j) {
            const int c2i = 2 * (lane + j * 64);
            cpA[j] = cp4[c2i];
            cpB[j] = cp4[c2i + 1];
        }
        float4 acc[2 * NH4];
#pragma unroll
        for (int i = 0; i < 2 * NH4; ++i) acc[i] = make_float4(0.f, 0.f, 0.f, 0.f);
        esum = 0.f;

#pragma unroll
        for (int rr = 0; rr < RPW_C; ++rr) {
            float4 znext[NH4];
            if (rr + 1 < RPW_C) {
                const float4* zn = zh + (size_t)(rr + 1) * (D_DIM / 8);
#pragma unroll
                for (int j = 0; j < NH4; ++j) znext[j] = zn[lane + j * 64];
            }
            float dot = 0.f;
#pragma unroll
            for (int j = 0; j < NH4; ++j) {
                const __half2* hp = (const __half2*)&hcur[j];
                const float2 a0 = __half22float2(hp[0]);
                const float2 a1 = __half22float2(hp[1]);
                const float2 a2 = __half22float2(hp[2]);
                const float2 a3 = __half22float2(hp[3]);
                dot += a0.x * cpA[j].x + a0.y * cpA[j].y
                     + a1.x * cpA[j].z + a1.y * cpA[j].w
                     + a2.x * cpB[j].x + a2.y * cpB[j].y
                     + a3.x * cpB[j].z + a3.y * cpB[j].w;
            }
            dot = wave_reduce_sum(dot);
            b1reg[rr] = dot;
            const float w = expf(dot);
            esum += w;
#pragma unroll
            for (int j = 0; j < NH4; ++j) {
                const __half2* hp = (const __half2*)&hcur[j];
                const float2 a0 = __half22float2(hp[0]);
                const float2 a1 = __half22float2(hp[1]);
                const float2 a2 = __half22float2(hp[2]);
                const float2 a3 = __half22float2(hp[3]);
                acc[2 * j].x     += w * a0.x;  acc[2 * j].y     += w * a0.y;
                acc[2 * j].z     += w * a1.x;  acc[2 * j].w     += w * a1.y;
                acc[2 * j + 1].x += w * a2.x;  acc[2 * j + 1].y += w * a2.y;
                acc[2 * j + 1].z += w * a3.x;  acc[2 * j + 1].w += w * a3.y;
            }
            if (rr + 1 < RPW_C) {
#pragma unroll
                for (int j = 0; j < NH4; ++j) hcur[j] = znext[j];
            }
        }

#pragma unroll
        for (int j = 0; j < NH4; ++j) {
            const int c2i = 2 * (lane + j * 64);
            s_comb[wid][c2i]     = acc[2 * j];
            s_comb[wid][c2i + 1] = acc[2 * j + 1];
        }
        if (lane == 0) e_comb[wid] = esum;
        __syncthreads();
        uint2* ps = (uint2*)(part_s + (size_t)blk * D_DIM);
#pragma unroll
        for (int j = 0; j < 2; ++j) {
            const int f = t + j * 256;
            const float4 a  = s_comb[0][f];
            const float4 b4 = s_comb[1][f];
            const float4 c4 = s_comb[2][f];
            const float4 d4 = s_comb[3][f];
            float4 s;
            s.x = (a.x + b4.x) + (c4.x + d4.x);
            s.y = (a.y + b4.y) + (c4.y + d4.y);
            s.z = (a.z + b4.z) + (c4.z + d4.z);
            s.w = (a.w + b4.w) + (c4.w + d4.w);
            ps[f] = pack4(s);
        }
        if (t == 0) part_e[blk] = (e_comb[0] + e_comb[1]) + (e_comb[2] + e_comb[3]);
    }

    gsync(grid);   // phase-1 partials visible

#pragma unroll
    for (int j = 0; j < NH4; ++j) hcur[j] = zh[lane + j * 64];  // re-prefetch

    if (blk < C_CLS) {   // exp-weighted reduce -> c2
        float es = 0.f;
#pragma unroll
        for (int p = 0; p < BPC_C; ++p) es += part_e[blk * BPC_C + p];
        class_reduce_c(part_s + (size_t)blk * BPC_C * D_DIM, 1.f / es,
                       c_buf + (size_t)blk * D_DIM, t, lane, wid, e_comb);
    }

    gsync(grid);   // c2 ready

    // ============ phase 2: b2 = b1 + z16.c2, final weights =================
    {
        const float4* cp4 = (const float4*)(c_buf + (size_t)cls * D_DIM);
        float4 cpA[NH4], cpB[NH4];
#pragma unroll
        for (int j = 0; j < NH4; ++j) {
            const int c2i = 2 * (lane + j * 64);
            cpA[j] = cp4[c2i];
            cpB[j] = cp4[c2i + 1];
        }
        float4 acc[2 * NH4];
#pragma unroll
        for (int i = 0; i < 2 * NH4; ++i) acc[i] = make_float4(0.f, 0.f, 0.f, 0.f);
        esum = 0.f;

#pragma unroll
        for (int rr = 0; rr < RPW_C; ++rr) {
            float4 znext[NH4];
            if (rr + 1 < RPW_C) {
                const float4* zn = zh + (size_t)(rr + 1) * (D_DIM / 8);
#pragma unroll
                for (int j = 0; j < NH4; ++j) znext[j] = zn[lane + j * 64];
            }
            float dot = 0.f;
#pragma unroll
            for (int j = 0; j < NH4; ++j) {
                const __half2* hp = (const __half2*)&hcur[j];
                const float2 a0 = __half22float2(hp[0]);
                const float2 a1 = __half22float2(hp[1]);
                const float2 a2 = __half22float2(hp[2]);
                const float2 a3 = __half22float2(hp[3]);
                dot += a0.x * cpA[j].x + a0.y * cpA[j].y
                     + a1.x * cpA[j].z + a1.y * cpA[j].w
                     + a2.x * cpB[j].x + a2.y * cpB[j].y
                     + a3.x * cpB[j].z + a3.y * cpB[j].w;
            }
            dot = wave_reduce_sum(dot);
            const float w = expf(b1reg[rr] + dot);
            esum += w;
#pragma unroll
            for (int j = 0; j < NH4; ++j) {
                const __half2* hp = (const __half2*)&hcur[j];
                const float2 a0 = __half22float2(hp[0]);
                const float2 a1 = __half22float2(hp[1]);
                const float2 a2 = __half22float2(hp[2]);
                const float2 a3 = __half22float2(hp[3]);
                acc[2 * j].x     += w * a0.x;  acc[2 * j].y     += w * a0.y;
                acc[2 * j].z     += w * a1.x;  acc[2 * j].w     += w * a1.y;
                acc[2 * j + 1].x += w * a2.x;  acc[2 * j + 1].y += w * a2.y;
                acc[2 * j + 1].z += w * a3.x;  acc[2 * j + 1].w += w * a3.y;
            }
            if (rr + 1 < RPW_C) {
#pragma unroll
                for (int j = 0; j < NH4; ++j) hcur[j] = znext[j];
            }
        }

#pragma unroll
        for (int j = 0; j < NH4; ++j) {
            const int c2i = 2 * (lane + j * 64);
            s_comb[wid][c2i]     = acc[2 * j];
            s_comb[wid][c2i + 1] = acc[2 * j + 1];
        }
        if (lane == 0) e_comb[wid] = esum;
        __syncthreads();
        uint2* ps = (uint2*)(part_s + (size_t)blk * D_DIM);
#pragma unroll
        for (int j = 0; j < 2; ++j) {
            const int f = t + j * 256;
            const float4 a  = s_comb[0][f];
            const float4 b4 = s_comb[1][f];
            const float4 c4 = s_comb[2][f];
            const float4 d4 = s_comb[3][f];
            float4 s;
            s.x = (a.x + b4.x) + (c4.x + d4.x);
            s.y = (a.y + b4.y) + (c4.y + d4.y);
            s.z = (a.z + b4.z) + (c4.z + d4.z);
            s.w = (a.w + b4.w) + (c4.w + d4.w);
            ps[f] = pack4(s);
        }
        if (t == 0) part_e[blk] = (e_comb[0] + e_comb[1]) + (e_comb[2] + e_comb[3]);
    }

    gsync(grid);   // phase-2 partials visible

    if (blk < C_CLS) {   // final reduce -> out
        float es = 0.f;
#pragma unroll
        for (int p = 0; p < BPC_C; ++p) es += part_e[blk * BPC_C + p];
        class_reduce_c(part_s + (size_t)blk * BPC_C * D_DIM, 1.f / es,
                       out + (size_t)blk * D_DIM, t, lane, wid, e_comb);
    }
}

// ====================== fallback path (round-7, proven) ====================

__global__ __launch_bounds__(256)
void route_pass0(const float* __restrict__ z,
                 __half* __restrict__ z16,
                 __half* __restrict__ part_s,
                 float* __restrict__ part_e)
{
    __shared__ float4 s_comb[NWAVES][D_DIM / 4];
    __shared__ float  e_comb[NWAVES];

    const int blk  = blockIdx.x;
    const int cls  = blk >> 4;
    const int bic  = blk & (BPC_F - 1);
    const int lane = threadIdx.x & 63;
    const int wid  = threadIdx.x >> 6;
    const int t    = threadIdx.x;

    float4 acc[NF4];
#pragma unroll
    for (int i = 0; i < NF4; ++i) acc[i] = make_float4(0.f, 0.f, 0.f, 0.f);
    float esum = 0.f;

    const int k0 = bic * RPB_F + wid * RPW_F;
    const float4* __restrict__ zb =
        (const float4*)(z + ((size_t)cls * K_SHOTS + k0) * D_DIM);

    float4 zcur[NF4];
#pragma unroll
    for (int i = 0; i < NF4; ++i) zcur[i] = zb[lane + i * 64];

#pragma unroll
    for (int r = 0; r < RPW_F; ++r) {
        float4 znext[NF4];
        if (r + 1 < RPW_F) {
            const float4* zn = zb + (size_t)(r + 1) * (D_DIM / 4);
#pragma unroll
            for (int i = 0; i < NF4; ++i) znext[i] = zn[lane + i * 64];
        }
        float n2 = 0.f;
#pragma unroll
        for (int i = 0; i < NF4; ++i)
            n2 += zcur[i].x * zcur[i].x + zcur[i].y * zcur[i].y
                + zcur[i].z * zcur[i].z + zcur[i].w * zcur[i].w;
        n2 = wave_reduce_sum(n2);
        const float sc = sqrtf(n2) / (1.f + n2);

        uint2* p16 = (uint2*)(z16 + ((size_t)cls * K_SHOTS + k0 + r) * D_DIM);
#pragma unroll
        for (int i = 0; i < NF4; ++i) {
            float4 s;
            s.x = sc * zcur[i].x; s.y = sc * zcur[i].y;
            s.z = sc * zcur[i].z; s.w = sc * zcur[i].w;
            p16[lane + i * 64] = pack4(s);
            acc[i].x += s.x; acc[i].y += s.y; acc[i].z += s.z; acc[i].w += s.w;
        }
        esum += 1.f;
        if (r + 1 < RPW_F) {
#pragma unroll
            for (int i = 0; i < NF4; ++i) zcur[i] = znext[i];
        }
    }

#pragma unroll
    for (int i = 0; i < NF4; ++i) s_comb[wid][lane + i * 64] = acc[i];
    if (lane == 0) e_comb[wid] = esum;
    __syncthreads();

    uint2* ps = (uint2*)(part_s + (size_t)blk * D_DIM);
#pragma unroll
    for (int j = 0; j < 2; ++j) {
        const int f = t + j * 256;
        const float4 a  = s_comb[0][f];
        const float4 b4 = s_comb[1][f];
        const float4 c4 = s_comb[2][f];
        const float4 d4 = s_comb[3][f];
        float4 s;
        s.x = (a.x + b4.x) + (c4.x + d4.x);
        s.y = (a.y + b4.y) + (c4.y + d4.y);
        s.z = (a.z + b4.z) + (c4.z + d4.z);
        s.w = (a.w + b4.w) + (c4.w + d4.w);
        ps[f] = pack4(s);
    }
    if (t == 0) part_e[blk] = (e_comb[0] + e_comb[1]) + (e_comb[2] + e_comb[3]);
}

template <int PASS>
__global__ __launch_bounds__(256)
void route_pass_h(const __half* __restrict__ z16,
                  float* __restrict__ bvec,
                  const float* __restrict__ c_prev,
                  __half* __restrict__ part_s,
                  float* __restrict__ part_e)
{
    __shared__ float4 s_comb[NWAVES][D_DIM / 4];
    __shared__ float  e_comb[NWAVES];

    const int rawblk = blockIdx.x;
    const int blk  = (PASS == 1) ? (NBLK_F - 1 - rawblk) : rawblk;
    const int cls  = blk >> 4;
    const int bic  = blk & (BPC_F - 1);
    const int lane = threadIdx.x & 63;
    const int wid  = threadIdx.x >> 6;
    const int t    = threadIdx.x;

    const float4* cp4 = (const float4*)(c_prev + (size_t)cls * D_DIM);
    float4 cpA[NH4], cpB[NH4];
#pragma unroll
    for (int j = 0; j < NH4; ++j) {
        const int c2i = 2 * (lane + j * 64);
        cpA[j] = cp4[c2i];
        cpB[j] = cp4[c2i + 1];
    }

    float4 acc[2 * NH4];
#pragma unroll
    for (int i = 0; i < 2 * NH4; ++i) acc[i] = make_float4(0.f, 0.f, 0.f, 0.f);
    float esum = 0.f;

    const int k0 = bic * RPB_F + wid * RPW_F;
    const float4* __restrict__ zb =
        (const float4*)(z16 + ((size_t)cls * K_SHOTS + k0) * D_DIM);

    const int r0    = (PASS == 1) ? (RPW_F - 1) : 0;
    const int rstep = (PASS == 1) ? -1 : 1;

    float4 zcur[NH4];
#pragma unroll
    for (int j = 0; j < NH4; ++j)
        zcur[j] = zb[(size_t)r0 * (D_DIM / 8) + lane + j * 64];

#pragma unroll
    for (int rr = 0; rr < RPW_F; ++rr) {
        const int r = r0 + rr * rstep;
        float4 znext[NH4];
        if (rr + 1 < RPW_F) {
            const float4* zn = zb + (size_t)(r + rstep) * (D_DIM / 8);
#pragma unroll
            for (int j = 0; j < NH4; ++j) znext[j] = zn[lane + j * 64];
        }

        float dot = 0.f;
#pragma unroll
        for (int j = 0; j < NH4; ++j) {
            const __half2* hp = (const __half2*)&zcur[j];
            const float2 a0 = __half22float2(hp[0]);
            const float2 a1 = __half22float2(hp[1]);
            const float2 a2 = __half22float2(hp[2]);
            const float2 a3 = __half22float2(hp[3]);
            dot += a0.x * cpA[j].x + a0.y * cpA[j].y
                 + a1.x * cpA[j].z + a1.y * cpA[j].w
                 + a2.x * cpB[j].x + a2.y * cpB[j].y
                 + a3.x * cpB[j].z + a3.y * cpB[j].w;
        }
        dot = wave_reduce_sum(dot);

        const int k = k0 + r;
        float bnew = dot;
        if (PASS == 2) bnew += bvec[cls * K_SHOTS + k];
        if (PASS == 1 && lane == 0) bvec[cls * K_SHOTS + k] = bnew;
        const float w = expf(bnew);
        esum += w;

#pragma unroll
        for (int j = 0; j < NH4; ++j) {
            const __half2* hp = (const __half2*)&zcur[j];
            const float2 a0 = __half22float2(hp[0]);
            const float2 a1 = __half22float2(hp[1]);
            const float2 a2 = __half22float2(hp[2]);
            const float2 a3 = __half22float2(hp[3]);
            acc[2 * j].x     += w * a0.x;  acc[2 * j].y     += w * a0.y;
            acc[2 * j].z     += w * a1.x;  acc[2 * j].w     += w * a1.y;
            acc[2 * j + 1].x += w * a2.x;  acc[2 * j + 1].y += w * a2.y;
            acc[2 * j + 1].z += w * a3.x;  acc[2 * j + 1].w += w * a3.y;
        }

        if (rr + 1 < RPW_F) {
#pragma unroll
            for (int j = 0; j < NH4; ++j) zcur[j] = znext[j];
        }
    }

#pragma unroll
    for (int j = 0; j < NH4; ++j) {
        const int c2i = 2 * (lane + j * 64);
        s_comb[wid][c2i]     = acc[2 * j];
        s_comb[wid][c2i + 1] = acc[2 * j + 1];
    }
    if (lane == 0) e_comb[wid] = esum;
    __syncthreads();

    uint2* ps = (uint2*)(part_s + (size_t)blk * D_DIM);
#pragma unroll
    for (int j = 0; j < 2; ++j) {
        const int f = t + j * 256;
        const float4 a  = s_comb[0][f];
        const float4 b4 = s_comb[1][f];
        const float4 c4 = s_comb[2][f];
        const float4 d4 = s_comb[3][f];
        float4 s;
        s.x = (a.x + b4.x) + (c4.x + d4.x);
        s.y = (a.y + b4.y) + (c4.y + d4.y);
        s.z = (a.z + b4.z) + (c4.z + d4.z);
        s.w = (a.w + b4.w) + (c4.w + d4.w);
        ps[f] = pack4(s);
    }
    if (t == 0) part_e[blk] = (e_comb[0] + e_comb[1]) + (e_comb[2] + e_comb[3]);
}

__global__ __launch_bounds__(256)
void reduce_squash(const __half* __restrict__ part_s,
                   const float* __restrict__ part_e,
                   float* __restrict__ c_out)
{
    __shared__ float wred[NWAVES];
    const int cls  = blockIdx.x;
    const int t    = threadIdx.x;
    const int lane = t & 63;
    const int wid  = t >> 6;

    float esum = 0.f;
#pragma unroll
    for (int p = 0; p < BPC_F; ++p) esum += part_e[cls * BPC_F + p];
    const float inv = 1.f / esum;

    float4 m[2];
    float n2p = 0.f;
#pragma unroll
    for (int j = 0; j < 2; ++j) {
        const int f = t + j * 256;
        float4 s = make_float4(0.f, 0.f, 0.f, 0.f);
#pragma unroll
        for (int p = 0; p < BPC_F; ++p) {
            const uint2 v =
                ((const uint2*)(part_s + (size_t)(cls * BPC_F + p) * D_DIM))[f];
            const __half2* hv = (const __half2*)&v;
            const float2 lo = __half22float2(hv[0]);
            const float2 hi = __half22float2(hv[1]);
            s.x += lo.x; s.y += lo.y; s.z += hi.x; s.w += hi.y;
        }
        m[j].x = s.x * inv; m[j].y = s.y * inv;
        m[j].z = s.z * inv; m[j].w = s.w * inv;
        n2p += m[j].x * m[j].x + m[j].y * m[j].y
             + m[j].z * m[j].z + m[j].w * m[j].w;
    }
    float n2 = wave_reduce_sum(n2p);
    if (lane == 0) wred[wid] = n2;
    __syncthreads();
    n2 = (wred[0] + wred[1]) + (wred[2] + wred[3]);
    const float fac = sqrtf(n2) / (1.f + n2);

    float4* co = (float4*)(c_out + (size_t)cls * D_DIM);
#pragma unroll
    for (int j = 0; j < 2; ++j) {
        const int f = t + j * 256;
        float4 o;
        o.x = m[j].x * fac; o.y = m[j].y * fac;
        o.z = m[j].z * fac; o.w = m[j].w * fac;
        co[f] = o;
    }
}

extern "C" void kernel_launch(void* const* d_in, const int* in_sizes, int n_in,
                              void* d_out, int out_size, void* d_ws, size_t ws_size,
                              hipStream_t stream)
{
    const float* z = (const float*)d_in[0];
    float* outp = (float*)d_out;
    float* ws   = (float*)d_ws;

    float*  bvec   = ws;                                        // C*K f32 (fallback)
    float*  part_e = bvec + C_CLS * K_SHOTS;                    // NBLK_F f32
    float*  c_buf  = part_e + NBLK_F;                           // C*D f32
    __half* part_s = (__half*)(c_buf + (size_t)C_CLS * D_DIM);  // NBLK_F*D half (4 MiB)
    __half* z16    = part_s + (size_t)NBLK_F * D_DIM;           // C*K*D half (128 MiB)
    // total ws ~134 MB (< 1 GB)

    // Deterministic path choice: occupancy pre-check (host query, capture-safe)
    // + synchronous launch status. Same decision on every call.
    int occ = 0;
    hipError_t qerr = hipOccupancyMaxActiveBlocksPerMultiprocessor(
        &occ, (const void*)induction_fused, 256, 0);
    hipError_t lerr = hipErrorUnknown;
    if (qerr == hipSuccess && occ >= 2) {   // 2 blocks/CU x 256 CU >= 512-block grid
        void* args[6];
        args[0] = (void*)&z;
        args[1] = (void*)&z16;
        args[2] = (void*)&part_s;
        args[3] = (void*)&part_e;
        args[4] = (void*)&c_buf;
        args[5] = (void*)&outp;
        lerr = hipLaunchCooperativeKernel((const void*)induction_fused,
                                          dim3(NBLK_C), dim3(256), args, 0, stream);
    }
    if (lerr != hipSuccess) {
        (void)hipGetLastError();   // clear sticky error; fall back to proven path
        route_pass0<<<NBLK_F, 256, 0, stream>>>(z, z16, part_s, part_e);
        reduce_squash<<<C_CLS, 256, 0, stream>>>(part_s, part_e, c_buf);
        route_pass_h<1><<<NBLK_F, 256, 0, stream>>>(z16, bvec, c_buf, part_s, part_e);
        reduce_squash<<<C_CLS, 256, 0, stream>>>(part_s, part_e, c_buf);
        route_pass_h<2><<<NBLK_F, 256, 0, stream>>>(z16, bvec, c_buf, part_s, part_e);
        reduce_squash<<<C_CLS, 256, 0, stream>>>(part_s, part_e, outp);
    }
}